// Round 10
// baseline (298.736 us; speedup 1.0000x reference)
//
#include <hip/hip_runtime.h>
#include <math.h>

namespace {

constexpr int NF   = 256;   // n_feature / tokens
constexpr int EH   = 128;   // embedder hidden
constexpr int E    = 64;    // embedded dim
constexpr int H    = 64;    // lstm size
constexpr int SHD  = 256;   // shared hidden
constexpr int SD   = 128;   // shared dim
constexpr int NA   = 257;   // n_action
constexpr int NSHUF = 4;

__device__ __forceinline__ float fsig(float x) {
  return 1.f / (1.f + __expf(-x));
}
__device__ __forceinline__ float ftanh(float x) {
  return 1.f - 2.f / (__expf(2.f * x) + 1.f);
}
__device__ __forceinline__ float4 f4ma(float s, const float4 w, float4 a) {
  a.x = fmaf(s, w.x, a.x); a.y = fmaf(s, w.y, a.y);
  a.z = fmaf(s, w.z, a.z); a.w = fmaf(s, w.w, a.w);
  return a;
}

// Allocator model (r2-r9, CONFIRMED r9): it lands one tier below the declared
// cap. (512,2) => cap 256 => lands 128 VGPR, no spill for a <=110 live set.
// This round: r6's register-resident emb (phase 2 from registers, no LDS
// emb array / no retire) now that the 128-VGPR budget is reliable.
__global__ __launch_bounds__(512, 2)
void seqnet(
    const float* __restrict__ state, const int* __restrict__ acquired,
    const float* __restrict__ We1, const float* __restrict__ be1,
    const float* __restrict__ We2, const float* __restrict__ be2,
    const float* __restrict__ Wih, const float* __restrict__ Whh,
    const float* __restrict__ bih, const float* __restrict__ bhh,
    const float* __restrict__ Ws1, const float* __restrict__ bs1,
    const float* __restrict__ Ws2, const float* __restrict__ bs2,
    const float* __restrict__ Wp1, const float* __restrict__ bp1,
    const float* __restrict__ Wp2, const float* __restrict__ bp2,
    const float* __restrict__ Wv1, const float* __restrict__ bv1,
    const float* __restrict__ Wv2, const float* __restrict__ bv2,
    float* __restrict__ out)
{
  const int b    = blockIdx.x;
  const int t    = threadIdx.x;   // 0..511
  const int lane = t & 63;
  const int wid  = t >> 6;        // 0..7

  __shared__ __align__(16) float h_s[32 * NF];     // 32 KB: h K-tile [k][tok]
  __shared__ __align__(16) float we2_s[32 * E];    // 8 KB: We2 K-tile [k][col]
  __shared__ int   id_l[NF];
  __shared__ __align__(16) float val_l[NF];
  __shared__ __align__(16) float w_s[NF];          // logits, then softmax w
  __shared__ __align__(16) float red_s[512];
  __shared__ __align__(16) float partial[8][E];    // per-wave attended partials
  __shared__ __align__(16) float t1_s[SHD];
  __shared__ __align__(16) float sh_s[SD];
  __shared__ __align__(16) float a1_s[SD];
  __shared__ __align__(16) float v1_s[SD];
  __shared__ int   wcnt[4];
  __shared__ float wred[8];
  __shared__ __align__(16) float qt_s[H];
  __shared__ float ct_s[H];
  __shared__ __align__(16) float att_s[E];
  __shared__ float v_scalar;

  // ---------------- phase 0: closed-form "argsort" ----------------
  int ai = 0, pin = 0;
  if (t < NF) {
    id_l[t] = 0; val_l[t] = 0.f;                   // tok >= L: id 0, val 0
    ai = (acquired[b * NF + t] != 0) ? 1 : 0;
    const unsigned long long mask = __ballot(ai);
    pin = __popcll(mask & ((1ull << lane) - 1ull));
    if (lane == 0) wcnt[wid] = __popcll(mask);     // wid 0..3 here
  }
  if (t < H) { qt_s[t] = 0.f; ct_s[t] = 0.f; att_s[t] = 0.f; }
  __syncthreads();
  const int L = wcnt[0] + wcnt[1] + wcnt[2] + wcnt[3];
  if (t < NF && ai) {
    int pexcl = pin;
    #pragma unroll
    for (int w = 0; w < 4; ++w) if (w < wid) pexcl += wcnt[w];
    const int rank = L - pexcl - 1;                // # acquired with index > t
    id_l[rank]  = t + 1;
    val_l[rank] = state[b * NF + t];
  }
  __syncthreads();

  // ---------------- phase 1: embedder as block GEMM ----------------
  // Step A role: thread (p = t>>8, tokA = t&255) computes h[kb..kb+15][tokA].
  // Step B role: thread (tg = t>>4 owns 8 toks, cg = t&15 owns 4 cols).
  const int pA   = t >> 8;
  const int tokA = t & 255;
  const int idA  = id_l[tokA];
  const float vA = val_l[tokA];
  const float* __restrict__ w1r = We1 + idA * EH;
  const int tg8 = (t >> 4) * 8;
  const int cg4 = (t & 15) * 4;

  float4 a0{0,0,0,0}, a1{0,0,0,0}, a2{0,0,0,0}, a3{0,0,0,0};
  float4 a4{0,0,0,0}, a5{0,0,0,0}, a6{0,0,0,0}, a7{0,0,0,0};

  for (int kt = 0; kt < 4; ++kt) {
    // Step A: h tile [32][256]
    {
      const int kb = kt * 32 + pA * 16;
      #pragma unroll
      for (int q = 0; q < 4; ++q) {
        const float4 wr = *(const float4*)(w1r + kb + q * 4);   // per-lane gather
        const float4 w0 = *(const float4*)(We1 + kb + q * 4);   // uniform
        const float4 bb = *(const float4*)(be1 + kb + q * 4);   // uniform
        const int r = (pA * 16 + q * 4) * NF + tokA;
        h_s[r]           = fmaxf(fmaf(vA, w0.x, wr.x) + bb.x, 0.f);
        h_s[r + NF]      = fmaxf(fmaf(vA, w0.y, wr.y) + bb.y, 0.f);
        h_s[r + 2 * NF]  = fmaxf(fmaf(vA, w0.z, wr.z) + bb.z, 0.f);
        h_s[r + 3 * NF]  = fmaxf(fmaf(vA, w0.w, wr.w) + bb.w, 0.f);
      }
      // We2 K-tile slice [32][64]: one float4 per thread
      const int r2 = t >> 4, c2 = (t & 15) * 4;
      *(float4*)&we2_s[r2 * E + c2] = *(const float4*)(We2 + (kt * 32 + r2) * E + c2);
    }
    __syncthreads();
    // Step B: acc[8 tok][4 col] += h[k][tok] * We2[k][col]
    if (tg8 < L) {   // wave-mostly-uniform skip of dead tokens
      #pragma unroll 2
      for (int k = 0; k < 32; ++k) {
        const float4 w2 = *(const float4*)&we2_s[k * E + cg4];
        const float4 ha = *(const float4*)&h_s[k * NF + tg8];
        a0 = f4ma(ha.x, w2, a0); a1 = f4ma(ha.y, w2, a1);
        a2 = f4ma(ha.z, w2, a2); a3 = f4ma(ha.w, w2, a3);
        const float4 hb = *(const float4*)&h_s[k * NF + tg8 + 4];
        a4 = f4ma(hb.x, w2, a4); a5 = f4ma(hb.y, w2, a5);
        a6 = f4ma(hb.z, w2, a6); a7 = f4ma(hb.w, w2, a7);
      }
    }
    __syncthreads();   // protect h_s/we2_s overwrite next tile
  }
  {  // + be2 (all tokens; masked by w=0 beyond L)
    const float4 b2 = *(const float4*)(be2 + cg4);
    a0.x+=b2.x; a0.y+=b2.y; a0.z+=b2.z; a0.w+=b2.w;
    a1.x+=b2.x; a1.y+=b2.y; a1.z+=b2.z; a1.w+=b2.w;
    a2.x+=b2.x; a2.y+=b2.y; a2.z+=b2.z; a2.w+=b2.w;
    a3.x+=b2.x; a3.y+=b2.y; a3.z+=b2.z; a3.w+=b2.w;
    a4.x+=b2.x; a4.y+=b2.y; a4.z+=b2.z; a4.w+=b2.w;
    a5.x+=b2.x; a5.y+=b2.y; a5.z+=b2.z; a5.w+=b2.w;
    a6.x+=b2.x; a6.y+=b2.y; a6.z+=b2.z; a6.w+=b2.w;
    a7.x+=b2.x; a7.y+=b2.y; a7.z+=b2.z; a7.w+=b2.w;
  }

  // ---------------- phase 2: attention + LSTM (emb in registers) ----------
  if (L > 0) {
    const float invL = 1.f / (float)L;
    for (int it = 0; it < NSHUF; ++it) {
      if (it == 0) {
        // qt == 0 -> masked logits all 0 -> uniform softmax over first L
        if (t < NF) w_s[t] = (t < L) ? invL : 0.f;
        __syncthreads();
      } else {
        // logits: per-token dot(emb, qt); reduce over 16 col-group lanes
        const float4 q4 = *(const float4*)&qt_s[cg4];
        float p0 = fmaf(a0.x,q4.x, fmaf(a0.y,q4.y, fmaf(a0.z,q4.z, a0.w*q4.w)));
        float p1 = fmaf(a1.x,q4.x, fmaf(a1.y,q4.y, fmaf(a1.z,q4.z, a1.w*q4.w)));
        float p2 = fmaf(a2.x,q4.x, fmaf(a2.y,q4.y, fmaf(a2.z,q4.z, a2.w*q4.w)));
        float p3 = fmaf(a3.x,q4.x, fmaf(a3.y,q4.y, fmaf(a3.z,q4.z, a3.w*q4.w)));
        float p4 = fmaf(a4.x,q4.x, fmaf(a4.y,q4.y, fmaf(a4.z,q4.z, a4.w*q4.w)));
        float p5 = fmaf(a5.x,q4.x, fmaf(a5.y,q4.y, fmaf(a5.z,q4.z, a5.w*q4.w)));
        float p6 = fmaf(a6.x,q4.x, fmaf(a6.y,q4.y, fmaf(a6.z,q4.z, a6.w*q4.w)));
        float p7 = fmaf(a7.x,q4.x, fmaf(a7.y,q4.y, fmaf(a7.z,q4.z, a7.w*q4.w)));
        #pragma unroll
        for (int d = 1; d <= 8; d <<= 1) {
          p0 += __shfl_xor(p0, d); p1 += __shfl_xor(p1, d);
          p2 += __shfl_xor(p2, d); p3 += __shfl_xor(p3, d);
          p4 += __shfl_xor(p4, d); p5 += __shfl_xor(p5, d);
          p6 += __shfl_xor(p6, d); p7 += __shfl_xor(p7, d);
        }
        if ((t & 15) == 0) {
          w_s[tg8]     = p0; w_s[tg8 + 1] = p1;
          w_s[tg8 + 2] = p2; w_s[tg8 + 3] = p3;
          w_s[tg8 + 4] = p4; w_s[tg8 + 5] = p5;
          w_s[tg8 + 6] = p6; w_s[tg8 + 7] = p7;
        }
        __syncthreads();
        // softmax over 256 logits (first 256 threads), in-place into w_s
        float lg = -1e30f;
        if (t < NF && t < L) lg = w_s[t];
        float m = lg;
        #pragma unroll
        for (int d = 32; d > 0; d >>= 1) m = fmaxf(m, __shfl_xor(m, d));
        if (lane == 0 && wid < 4) wred[wid] = m;
        __syncthreads();
        m = fmaxf(fmaxf(wred[0], wred[1]), fmaxf(wred[2], wred[3]));
        const float pp = (t < NF && t < L) ? __expf(lg - m) : 0.f;
        float s = pp;
        #pragma unroll
        for (int d = 32; d > 0; d >>= 1) s += __shfl_xor(s, d);
        if (lane == 0 && wid < 4) wred[4 + wid] = s;
        __syncthreads();
        s = (wred[4] + wred[5]) + (wred[6] + wred[7]);
        if (t < NF) w_s[t] = pp / s;
        __syncthreads();
      }

      // attended[col] = sum_tok w[tok]*emb[tok][col] from registers
      {
        const float4 wv0 = *(const float4*)&w_s[tg8];
        const float4 wv1 = *(const float4*)&w_s[tg8 + 4];
        float4 ap{0,0,0,0};
        ap = f4ma(wv0.x, a0, ap); ap = f4ma(wv0.y, a1, ap);
        ap = f4ma(wv0.z, a2, ap); ap = f4ma(wv0.w, a3, ap);
        ap = f4ma(wv1.x, a4, ap); ap = f4ma(wv1.y, a5, ap);
        ap = f4ma(wv1.z, a6, ap); ap = f4ma(wv1.w, a7, ap);
        #pragma unroll
        for (int d = 16; d <= 32; d <<= 1) {
          ap.x += __shfl_xor(ap.x, d); ap.y += __shfl_xor(ap.y, d);
          ap.z += __shfl_xor(ap.z, d); ap.w += __shfl_xor(ap.w, d);
        }
        if (lane < 16) *(float4*)&partial[wid][cg4] = ap;
      }
      __syncthreads();
      if (t < E) {
        float s0 = 0.f;
        #pragma unroll
        for (int q = 0; q < 8; ++q) s0 += partial[q][t];
        att_s[t] = s0;
      }
      __syncthreads();

      // gates: waves 0-3: att@Wih, waves 4-7: qt@Whh (qt=0 at it0 -> 0)
      {
        const int col = t & 255;
        const int hf  = t >> 8;
        const float* __restrict__ W = hf ? Whh : Wih;
        const float* __restrict__ x = hf ? qt_s : att_s;
        float g0 = 0.f, g1 = 0.f, g2 = 0.f, g3 = 0.f;
        #pragma unroll
        for (int e = 0; e < 64; e += 4) {
          const float4 q = *(const float4*)(x + e);
          g0 = fmaf(q.x, W[(e)     * 256 + col], g0);
          g1 = fmaf(q.y, W[(e + 1) * 256 + col], g1);
          g2 = fmaf(q.z, W[(e + 2) * 256 + col], g2);
          g3 = fmaf(q.w, W[(e + 3) * 256 + col], g3);
        }
        red_s[t] = (g0 + g1) + (g2 + g3);
      }
      __syncthreads();
      if (t < 256) red_s[t] = red_s[t] + red_s[256 + t] + bih[t] + bhh[t];
      __syncthreads();
      if (t < H) {
        const float ig = red_s[t];
        const float fg = red_s[H + t];
        const float gg = red_s[2 * H + t];
        const float og = red_s[3 * H + t];
        float c = ct_s[t];
        c = fsig(fg) * c + fsig(ig) * ftanh(gg);
        ct_s[t] = c;
        qt_s[t] = fsig(og) * ftanh(c);
      }
      __syncthreads();
    }
  }

  // ---------------- phase 3: DuelingNet ----------------
  {
    const int col = t & 255;
    const int hf  = t >> 8;
    const float* __restrict__ x = hf ? qt_s : att_s;
    const float* __restrict__ W = Ws1 + hf * 64 * SHD;
    float x0 = 0.f, x1 = 0.f, x2 = 0.f, x3 = 0.f;
    #pragma unroll
    for (int k = 0; k < 64; k += 4) {
      const float4 q = *(const float4*)(x + k);
      x0 = fmaf(q.x, W[(k)     * SHD + col], x0);
      x1 = fmaf(q.y, W[(k + 1) * SHD + col], x1);
      x2 = fmaf(q.z, W[(k + 2) * SHD + col], x2);
      x3 = fmaf(q.w, W[(k + 3) * SHD + col], x3);
    }
    red_s[t] = (x0 + x1) + (x2 + x3);
  }
  __syncthreads();
  if (t < SHD) t1_s[t] = fmaxf(red_s[t] + red_s[256 + t] + bs1[t], 0.f);
  __syncthreads();
  {
    const int col = t & 127;
    const int qq  = t >> 7;
    const float* __restrict__ xq = t1_s + qq * 64;
    float x0 = 0.f, x1 = 0.f, x2 = 0.f, x3 = 0.f;
    #pragma unroll
    for (int k = 0; k < 64; k += 4) {
      const float4 q = *(const float4*)(xq + k);
      x0 = fmaf(q.x, Ws2[(qq * 64 + k)     * SD + col], x0);
      x1 = fmaf(q.y, Ws2[(qq * 64 + k + 1) * SD + col], x1);
      x2 = fmaf(q.z, Ws2[(qq * 64 + k + 2) * SD + col], x2);
      x3 = fmaf(q.w, Ws2[(qq * 64 + k + 3) * SD + col], x3);
    }
    red_s[t] = (x0 + x1) + (x2 + x3);
  }
  __syncthreads();
  if (t < SD)
    sh_s[t] = fmaxf((red_s[t] + red_s[128 + t]) + (red_s[256 + t] + red_s[384 + t]) + bs2[t], 0.f);
  __syncthreads();
  {
    const int col  = t & 127;
    const int half = (t >> 7) & 1;
    const int net  = t >> 8;
    const float* __restrict__ W  = (net ? Wv1 : Wp1) + half * 64 * SD;
    const float* __restrict__ xh = sh_s + half * 64;
    float x0 = 0.f, x1 = 0.f, x2 = 0.f, x3 = 0.f;
    #pragma unroll
    for (int k = 0; k < 64; k += 4) {
      const float4 q = *(const float4*)(xh + k);
      x0 = fmaf(q.x, W[(k)     * SD + col], x0);
      x1 = fmaf(q.y, W[(k + 1) * SD + col], x1);
      x2 = fmaf(q.z, W[(k + 2) * SD + col], x2);
      x3 = fmaf(q.w, W[(k + 3) * SD + col], x3);
    }
    red_s[t] = (x0 + x1) + (x2 + x3);
  }
  __syncthreads();
  if (t < SD) {
    a1_s[t] = fmaxf(red_s[t] + red_s[128 + t] + bp1[t], 0.f);
  } else if (t < 2 * SD) {
    const int tt = t - SD;
    v1_s[tt] = fmaxf(red_s[256 + tt] + red_s[384 + tt] + bv1[tt], 0.f);
  }
  __syncthreads();
  if (wid == 7) {
    float vv = fmaf(v1_s[lane], Wv2[lane], v1_s[lane + 64] * Wv2[lane + 64]);
    #pragma unroll
    for (int d = 32; d > 0; d >>= 1) vv += __shfl_xor(vv, d);
    if (lane == 0) v_scalar = vv + bv2[0];
  }
  float adv = 0.f;
  if (t < NA) {
    float x0 = 0.f, x1 = 0.f, x2 = 0.f, x3 = 0.f;
    #pragma unroll
    for (int k = 0; k < SD; k += 4) {
      const float4 a = *(const float4*)(a1_s + k);
      x0 = fmaf(a.x, Wp2[(k)     * NA + t], x0);
      x1 = fmaf(a.y, Wp2[(k + 1) * NA + t], x1);
      x2 = fmaf(a.z, Wp2[(k + 2) * NA + t], x2);
      x3 = fmaf(a.w, Wp2[(k + 3) * NA + t], x3);
    }
    adv = bp2[t] + (x0 + x1) + (x2 + x3);
  }
  float ss = adv;                       // 0 for t >= NA
  #pragma unroll
  for (int d = 32; d > 0; d >>= 1) ss += __shfl_xor(ss, d);
  if (lane == 0) wred[wid] = ss;
  __syncthreads();
  const float mean = ((wred[0] + wred[1]) + (wred[2] + wred[3]) +
                      (wred[4] + wred[5]) + (wred[6] + wred[7])) * (1.f / (float)NA);
  if (t < NA) out[b * NA + t] = v_scalar + adv - mean;
}

}  // namespace

extern "C" void kernel_launch(void* const* d_in, const int* in_sizes, int n_in,
                              void* d_out, int out_size, void* d_ws, size_t ws_size,
                              hipStream_t stream) {
  const float* state    = (const float*)d_in[0];
  const int*   acquired = (const int*)d_in[1];
  const float* We1 = (const float*)d_in[2];
  const float* be1 = (const float*)d_in[3];
  const float* We2 = (const float*)d_in[4];
  const float* be2 = (const float*)d_in[5];
  const float* Wih = (const float*)d_in[6];
  const float* Whh = (const float*)d_in[7];
  const float* bih = (const float*)d_in[8];
  const float* bhh = (const float*)d_in[9];
  const float* Ws1 = (const float*)d_in[10];
  const float* bs1 = (const float*)d_in[11];
  const float* Ws2 = (const float*)d_in[12];
  const float* bs2 = (const float*)d_in[13];
  const float* Wp1 = (const float*)d_in[14];
  const float* bp1 = (const float*)d_in[15];
  const float* Wp2 = (const float*)d_in[16];
  const float* bp2 = (const float*)d_in[17];
  const float* Wv1 = (const float*)d_in[18];
  const float* bv1 = (const float*)d_in[19];
  const float* Wv2 = (const float*)d_in[20];
  const float* bv2 = (const float*)d_in[21];
  float* out = (float*)d_out;

  const int Bn = in_sizes[0] / NF;   // 2048
  hipLaunchKernelGGL(seqnet, dim3(Bn), dim3(512), 0, stream,
                     state, acquired, We1, be1, We2, be2, Wih, Whh, bih, bhh,
                     Ws1, bs1, Ws2, bs2, Wp1, bp1, Wp2, bp2, Wv1, bv1, Wv2, bv2,
                     out);
}